// Round 1
// baseline (194.061 us; speedup 1.0000x reference)
//
#include <hip/hip_runtime.h>

#define HH 28
#define WW 28
#define NPIX 784          // 28*28
#define BLOCK 832         // 13 waves; threads 784..831 idle (5.8% waste)

// Each block: builds the 25-tap (byte-offset, coefficient) table in registers
// (thread = pixel), then loops over groups of 4 images: stage interleaved
// float4-per-pixel into LDS, gather 25 taps with ds_read_b128, 4 outputs/thread.
__global__ __launch_bounds__(BLOCK, 1) void axs_89807766159734_kernel(
    const float* __restrict__ x, const float* __restrict__ pos2d,
    const float* __restrict__ weight, float* __restrict__ out,
    int nGroups)
{
    __shared__ float4 lds[NPIX];
    const int p = threadIdx.x;
    const bool act = p < NPIX;

    float coef[25];
    int   boff[25];
    if (act) {
        const float p0 = pos2d[2*p],   p1 = pos2d[2*p + 1];
        const float sw = fmaxf(weight[p], 0.0f);          // relu(weight), folded into coef
        const float ce0 = rintf(p0), ce1 = rintf(p1);     // rintf == jnp.round (half-even)
#pragma unroll
        for (int t = 0; t < 25; ++t) {
            const int i0 = t / 5 - 2, i1 = t % 5 - 2;
            const float cr0 = ce0 + (float)i0, cr1 = ce1 + (float)i1;
            const int c0 = (int)cr0, c1 = (int)cr1;       // exact small ints
            const bool inb = (c0 >= 0) & (c0 < HH) & (c1 >= 0) & (c1 < WW);
            const int q0 = min(max(c0, 0), HH - 1);
            const int q1 = min(max(c1, 0), WW - 1);
            const float d0 = cr0 - p0, d1 = cr1 - p1;
            const float w = __expf(-0.5f * (d0*d0 + d1*d1));
            coef[t] = inb ? sw * w : 0.0f;                // mask folded into coef
            boff[t] = (q0 * WW + q1) * 16;                // byte offset into float4 LDS
        }
    }

    // Prefetch first group (4 coalesced dword loads per thread).
    int g = blockIdx.x;
    float v0 = 0.f, v1 = 0.f, v2 = 0.f, v3 = 0.f;
    if (g < nGroups && act) {
        const size_t base = (size_t)g * 4u * NPIX;
        v0 = x[base + p];
        v1 = x[base + NPIX + p];
        v2 = x[base + 2*NPIX + p];
        v3 = x[base + 3*NPIX + p];
    }

    for (; g < nGroups; g += gridDim.x) {
        __syncthreads();                     // previous group's compute done
        if (act) lds[p] = make_float4(v0, v1, v2, v3);   // ds_write_b128
        __syncthreads();

        // Prefetch next group's 4 floats while we compute from LDS.
        const int gn = g + gridDim.x;
        if (gn < nGroups && act) {
            const size_t nb = (size_t)gn * 4u * NPIX;
            v0 = x[nb + p];
            v1 = x[nb + NPIX + p];
            v2 = x[nb + 2*NPIX + p];
            v3 = x[nb + 3*NPIX + p];
        }

        if (act) {
            float a0 = 0.f, a1 = 0.f, a2 = 0.f, a3 = 0.f;
#pragma unroll
            for (int t = 0; t < 25; ++t) {
                const float4 v = *(const float4*)((const char*)lds + boff[t]); // ds_read_b128
                const float c = coef[t];
                a0 = fmaf(c, v.x, a0);
                a1 = fmaf(c, v.y, a1);
                a2 = fmaf(c, v.z, a2);
                a3 = fmaf(c, v.w, a3);
            }
            const size_t base = (size_t)g * 4u * NPIX;
            out[base + p]          = a0;
            out[base + NPIX + p]   = a1;
            out[base + 2*NPIX + p] = a2;
            out[base + 3*NPIX + p] = a3;
        }
    }
}

extern "C" void kernel_launch(void* const* d_in, const int* in_sizes, int n_in,
                              void* d_out, int out_size, void* d_ws, size_t ws_size,
                              hipStream_t stream) {
    const float* x      = (const float*)d_in[0];   // (B,1,28,28) fp32
    const float* pos2d  = (const float*)d_in[1];   // (28,28,2)   fp32
    const float* weight = (const float*)d_in[2];   // (28,28)     fp32
    float* out = (float*)d_out;

    const int B = in_sizes[0] / NPIX;              // 32768
    const int nGroups = B / 4;                     // 8192 (B divisible by 4)
    int blocks = nGroups < 1024 ? nGroups : 1024;  // ~2 blocks/CU resident

    hipLaunchKernelGGL(axs_89807766159734_kernel, dim3(blocks), dim3(BLOCK), 0, stream,
                       x, pos2d, weight, out, nGroups);
}